// Round 2
// baseline (1508.217 us; speedup 1.0000x reference)
//
#include <hip/hip_runtime.h>
#include <hip/hip_bf16.h>
#include <stdint.h>

typedef __attribute__((ext_vector_type(8))) short short8;   // 8 bf16 (4 VGPRs)
typedef __attribute__((ext_vector_type(4))) float f32x4;    // 4 fp32

#define NB_ 1536   // xg row width (2 dirs * 3 gates * 256)

// ---- workspace byte offsets (total ~64.3 MiB) ----
#define OFF_W0   0u          // W0cat bf16 [1536][256] (Wih0f rows 0..767, Wih0b 768..1535; K padded 200->256)
#define OFF_W1   786432u     // W1cat bf16 [1536][512]
#define OFF_WHH  2359296u    // Whh bf16 [4][768][256]  (l0f, l0b, l1f, l1b)
#define OFF_X    3932160u    // x bf16 [8192][256] rows = t*128+b, cols 200..255 zero
#define OFF_XG   8126464u    // xg fp32 [8192][1536] (reused by both layers)
#define OFF_HIST 58458112u   // h0 history bf16 [8192][512] (f cols 0..255, b 256..511)
#define OFF_HX   66846720u   // h exchange bf16 [2 parity][2 dir][128][256]
#define OFF_FS   67108864u   // final state fp32 [128][512]
#define OFF_CTR  67371008u   // 256 uints: spin counters (padded 64B apart), layer1 at +128 uints

static __device__ __forceinline__ unsigned short f2bf(float f) {
  uint32_t x = __float_as_uint(f);
  uint32_t r = (x + 0x7fffu + ((x >> 16) & 1u)) >> 16;   // RNE
  return (unsigned short)r;
}

// ---------------- weight convert (fp32 -> bf16, padded/stacked) + counter zero ----------------
__global__ __launch_bounds__(256) void prep_kernel(
    const float* s0, const float* s1, const float* s2, const float* s3,
    const float* s4, const float* s5, const float* s6, const float* s7,
    unsigned short* wsh, unsigned int* ctr) {
  int job = blockIdx.y;
  const float* srcs[8] = {s0, s1, s2, s3, s4, s5, s6, s7};
  const int scols[8] = {200, 200, 512, 512, 256, 256, 256, 256};
  const int shf[8]   = {8, 8, 9, 9, 8, 8, 8, 8};   // log2 dst pitch
  const unsigned doff[8] = {0u, 196608u, 393216u, 786432u,
                            1179648u, 1376256u, 1572864u, 1769472u}; // ushort elems
  int e = blockIdx.x * 256 + threadIdx.x;
  if (job == 0 && e < 256) ctr[e] = 0u;
  int sh = shf[job];
  int dp = 1 << sh;
  if (e >= (768 << sh)) return;
  int row = e >> sh, col = e & (dp - 1);
  int sc = scols[job];
  float v = (col < sc) ? srcs[job][row * sc + col] : 0.f;
  wsh[doff[job] + (unsigned)e] = f2bf(v);
}

// ---------------- embedding gather with OOV mask -> bf16 [8192][256] ----------------
__global__ __launch_bounds__(256) void embed_kernel(
    const int* wi, const float* emb, const float* oove, unsigned short* xb) {
  int tid = threadIdx.x;
  int rl = tid >> 5, c8 = tid & 31;
  int row = blockIdx.x * 8 + rl;          // 0..8191, row = t*128 + b
  int t = row >> 7, b = row & 127;
  int idx = wi[b * 64 + t];               // word_indices is [B=128][T=64]
  bool oov = (idx >= 100000);
  short8 v;
  if (c8 < 25) {                          // cols 0..199 (25*8 == 200 exactly)
    const float* src = oov ? (oove + c8 * 8) : (emb + (size_t)idx * 200 + c8 * 8);
#pragma unroll
    for (int e = 0; e < 8; ++e) v[e] = (short)f2bf(src[e]);
  } else {
#pragma unroll
    for (int e = 0; e < 8; ++e) v[e] = 0;
  }
  *(short8*)(xb + (size_t)row * 256 + c8 * 8) = v;
}

// ---------------- bf16 GEMM, B^T layout: C[m][n] = sum_k A[m][k]*Bw[n][k] ----------------
// tile 128x128, BK=64, 256 threads (2x2 waves, each 64x64 = 4x4 MFMA 16x16x32 tiles)
template<int KK>
__global__ __launch_bounds__(256) void gemm_bt(const unsigned short* A,
                                               const unsigned short* Bw, float* C) {
  __shared__ unsigned short sA[128 * 64];
  __shared__ unsigned short sB[128 * 64];
  int tid = threadIdx.x;
  int w = tid >> 6, l = tid & 63, lc = l & 15, half = l >> 4;
  int wr = w >> 1, wc = w & 1;
  int gm0 = blockIdx.x * 128, gn0 = blockIdx.y * 128;
  f32x4 acc[4][4];
#pragma unroll
  for (int i = 0; i < 4; ++i)
#pragma unroll
    for (int j = 0; j < 4; ++j) acc[i][j] = (f32x4){0.f, 0.f, 0.f, 0.f};
  for (int ks = 0; ks < KK; ks += 64) {
#pragma unroll
    for (int it = 0; it < 4; ++it) {
      int q = it * 4096 + tid * 16;       // byte offset within 16KB tile
      int row = q >> 7;
      int cole = (q & 127) >> 1;
      short8 va = *(const short8*)(A + (size_t)(gm0 + row) * KK + ks + cole);
      short8 vb = *(const short8*)(Bw + (size_t)(gn0 + row) * KK + ks + cole);
      *(short8*)(sA + (q >> 1)) = va;
      *(short8*)(sB + (q >> 1)) = vb;
    }
    __syncthreads();
#pragma unroll
    for (int kk = 0; kk < 2; ++kk) {
      short8 af[4], bq[4];
#pragma unroll
      for (int i = 0; i < 4; ++i)
        af[i] = *(const short8*)(sA + (wr * 64 + i * 16 + lc) * 64 + kk * 32 + half * 8);
#pragma unroll
      for (int j = 0; j < 4; ++j)
        bq[j] = *(const short8*)(sB + (wc * 64 + j * 16 + lc) * 64 + kk * 32 + half * 8);
#pragma unroll
      for (int i = 0; i < 4; ++i)
#pragma unroll
        for (int j = 0; j < 4; ++j)
          acc[i][j] = __builtin_amdgcn_mfma_f32_16x16x32_bf16(af[i], bq[j], acc[i][j], 0, 0, 0);
    }
    __syncthreads();
  }
#pragma unroll
  for (int i = 0; i < 4; ++i)
#pragma unroll
    for (int j = 0; j < 4; ++j)
#pragma unroll
      for (int r = 0; r < 4; ++r)
        C[(size_t)(gm0 + wr * 64 + i * 16 + half * 4 + r) * NB_ + gn0 + wc * 64 + j * 16 + lc] =
            acc[i][j][r];
}

// ---------------- recurrent scan: 32 WGs = 2 dir x 4 rowgroup x 4 unitgroup ----------------
// Whh B-fragments pinned in VGPRs (96 regs/lane); h exchanged via global + spin barrier.
template<int LAYER>
__global__ __launch_bounds__(256, 1) void recur_kernel(
    const float* xg, const unsigned short* WhhL,
    const float* bihf, const float* bhhf, const float* bihb, const float* bhhb,
    unsigned short* hx, unsigned short* hist, float* fs, unsigned int* ctr) {
  int wg = blockIdx.x;
  int dir = wg & 1, rg = (wg >> 1) & 3, ug = wg >> 3;
  int tid = threadIdx.x;
  int w = tid >> 6, l = tid & 63, lc = l & 15, half = l >> 4;
  int j = ug * 64 + w * 16 + lc;                    // owned hidden unit (col)
  const unsigned short* Wb = WhhL + (size_t)dir * 768 * 256;
  short8 bfrag[3][8];                               // [gate][k-tile], resident all 64 steps
#pragma unroll
  for (int g = 0; g < 3; ++g)
#pragma unroll
    for (int kt = 0; kt < 8; ++kt)
      bfrag[g][kt] = *(const short8*)(Wb + (size_t)(g * 256 + j) * 256 + kt * 32 + half * 8);
  const float* bih = dir ? bihb : bihf;
  const float* bhh = dir ? bhhb : bhhf;
  float bihv[3], bhhv[3];
#pragma unroll
  for (int g = 0; g < 3; ++g) { bihv[g] = bih[g * 256 + j]; bhhv[g] = bhh[g * 256 + j]; }
  float hprev[2][4] = {};                           // own h slice, fp32
  int rowbase = rg * 32;
  unsigned int* myctr = ctr + (dir * 4 + rg) * 16;  // padded 64B apart

  for (int s = 0; s < 64; ++s) {
    int tt = dir ? (63 - s) : s;
    f32x4 acc[2][3];
#pragma unroll
    for (int m = 0; m < 2; ++m)
#pragma unroll
      for (int g = 0; g < 3; ++g) acc[m][g] = (f32x4){0.f, 0.f, 0.f, 0.f};
    if (s > 0) {                                     // h(0) == 0 -> skip MFMA at s==0
      const unsigned short* hxr = hx + (size_t)((((s - 1) & 1) * 2 + dir) * 128) * 256;
#pragma unroll
      for (int m = 0; m < 2; ++m) {
        short8 afr[8];
#pragma unroll
        for (int kt = 0; kt < 8; ++kt)
          afr[kt] = *(const short8*)(hxr + (size_t)(rowbase + m * 16 + lc) * 256 + kt * 32 + half * 8);
#pragma unroll
        for (int kt = 0; kt < 8; ++kt) {
          acc[m][0] = __builtin_amdgcn_mfma_f32_16x16x32_bf16(afr[kt], bfrag[0][kt], acc[m][0], 0, 0, 0);
          acc[m][1] = __builtin_amdgcn_mfma_f32_16x16x32_bf16(afr[kt], bfrag[1][kt], acc[m][1], 0, 0, 0);
          acc[m][2] = __builtin_amdgcn_mfma_f32_16x16x32_bf16(afr[kt], bfrag[2][kt], acc[m][2], 0, 0, 0);
        }
      }
    }
    const float* xgt = xg + (size_t)(tt * 128 + rowbase) * NB_ + dir * 768;
    unsigned short* hxw = hx + (size_t)(((s & 1) * 2 + dir) * 128) * 256;
#pragma unroll
    for (int m = 0; m < 2; ++m) {
#pragma unroll
      for (int i = 0; i < 4; ++i) {
        int r = m * 16 + half * 4 + i;               // local batch row (C/D layout)
        const float* xr = xgt + (size_t)r * NB_;
        float xv0 = xr[j], xv1 = xr[256 + j], xv2 = xr[512 + j];
        float hr = acc[m][0][i] + bhhv[0];
        float hz = acc[m][1][i] + bhhv[1];
        float hn = acc[m][2][i] + bhhv[2];
        float rr = 1.f / (1.f + __expf(-(xv0 + bihv[0] + hr)));
        float zz = 1.f / (1.f + __expf(-(xv1 + bihv[1] + hz)));
        float pn = xv2 + bihv[2] + rr * hn;
        float nn = 2.f / (1.f + __expf(-2.f * pn)) - 1.f;   // tanh
        float hv = (1.f - zz) * nn + zz * hprev[m][i];
        hprev[m][i] = hv;
        unsigned short hb = f2bf(hv);
        int grow = rowbase + r;
        hxw[(size_t)grow * 256 + j] = hb;
        if (LAYER == 0) hist[(size_t)(tt * 128 + grow) * 512 + dir * 256 + j] = hb;
        if (LAYER == 1 && s == 63) fs[(size_t)grow * 512 + dir * 256 + j] = hv;
      }
    }
    // barrier among the 4 unit-group WGs sharing (dir, rowgroup)
    __threadfence();
    __syncthreads();
    if (tid == 0) {
      atomicAdd(myctr, 1u);
      unsigned target = 4u * (unsigned)(s + 1);
      while (__hip_atomic_load(myctr, __ATOMIC_RELAXED, __HIP_MEMORY_SCOPE_AGENT) < target)
        __builtin_amdgcn_s_sleep(2);
    }
    __syncthreads();
    __threadfence();
  }
}

// ---------------- final projection: out[b][o] = fs[b][:] . proj_W[o][:] + pb[o] ----------------
__global__ __launch_bounds__(256) void proj_kernel(const float* fs, const float* pW,
                                                   const float* pb, float* out) {
  __shared__ float sf[512];
  int b = blockIdx.x, o = threadIdx.x;
  for (int k = o; k < 512; k += 256) sf[k] = fs[b * 512 + k];
  __syncthreads();
  const float* wr_ = pW + (size_t)o * 512;
  float s = 0.f;
#pragma unroll 4
  for (int k = 0; k < 512; k += 4) {
    float4 wv = *(const float4*)(wr_ + k);
    s += wv.x * sf[k] + wv.y * sf[k + 1] + wv.z * sf[k + 2] + wv.w * sf[k + 3];
  }
  out[(size_t)b * 256 + o] = s + pb[o];
}

extern "C" void kernel_launch(void* const* d_in, const int* in_sizes, int n_in,
                              void* d_out, int out_size, void* d_ws, size_t ws_size,
                              hipStream_t stream) {
  const int*   wi    = (const int*)d_in[0];
  const float* emb   = (const float*)d_in[1];
  const float* oove  = (const float*)d_in[2];
  const float* Wih0f = (const float*)d_in[3];
  const float* Whh0f = (const float*)d_in[4];
  const float* bih0f = (const float*)d_in[5];
  const float* bhh0f = (const float*)d_in[6];
  const float* Wih0b = (const float*)d_in[7];
  const float* Whh0b = (const float*)d_in[8];
  const float* bih0b = (const float*)d_in[9];
  const float* bhh0b = (const float*)d_in[10];
  const float* Wih1f = (const float*)d_in[11];
  const float* Whh1f = (const float*)d_in[12];
  const float* bih1f = (const float*)d_in[13];
  const float* bhh1f = (const float*)d_in[14];
  const float* Wih1b = (const float*)d_in[15];
  const float* Whh1b = (const float*)d_in[16];
  const float* bih1b = (const float*)d_in[17];
  const float* bhh1b = (const float*)d_in[18];
  const float* projW = (const float*)d_in[19];
  const float* projb = (const float*)d_in[20];

  char* ws = (char*)d_ws;
  unsigned short* w0   = (unsigned short*)(ws + OFF_W0);
  unsigned short* w1   = (unsigned short*)(ws + OFF_W1);
  unsigned short* whh  = (unsigned short*)(ws + OFF_WHH);
  unsigned short* xb   = (unsigned short*)(ws + OFF_X);
  float*          xg   = (float*)(ws + OFF_XG);
  unsigned short* hist = (unsigned short*)(ws + OFF_HIST);
  unsigned short* hx   = (unsigned short*)(ws + OFF_HX);
  float*          fs   = (float*)(ws + OFF_FS);
  unsigned int*   ctr  = (unsigned int*)(ws + OFF_CTR);

  prep_kernel<<<dim3(1536, 8), 256, 0, stream>>>(Wih0f, Wih0b, Wih1f, Wih1b,
                                                 Whh0f, Whh0b, Whh1f, Whh1b,
                                                 (unsigned short*)ws, ctr);
  embed_kernel<<<1024, 256, 0, stream>>>(wi, emb, oove, xb);
  gemm_bt<256><<<dim3(64, 12), 256, 0, stream>>>(xb, w0, xg);
  recur_kernel<0><<<32, 256, 0, stream>>>(xg, whh, bih0f, bhh0f, bih0b, bhh0b,
                                          hx, hist, fs, ctr);
  gemm_bt<512><<<dim3(64, 12), 256, 0, stream>>>(hist, w1, xg);
  recur_kernel<1><<<32, 256, 0, stream>>>(xg, whh + 2 * 768 * 256, bih1f, bhh1f, bih1b, bhh1b,
                                          hx, hist, fs, ctr + 128);
  proj_kernel<<<128, 256, 0, stream>>>(fs, projW, projb, (float*)d_out);
}

// Round 6
// 686.703 us; speedup vs baseline: 2.1963x; 2.1963x over previous
//
#include <hip/hip_runtime.h>
#include <hip/hip_bf16.h>
#include <stdint.h>

typedef __attribute__((ext_vector_type(8))) short short8;   // 8 bf16 (4 VGPRs)
typedef __attribute__((ext_vector_type(4))) float f32x4;    // 4 fp32
typedef unsigned short usht;

// ---- workspace byte offsets ----
#define OFF_W0   0u          // W0cat bf16 [1536][256]  (Wih0f 0..767, Wih0b 768..1535; K pad 200->256)
#define OFF_W1   786432u     // W1cat bf16 [1536][512]
#define OFF_WHH  2359296u    // Whh bf16 [4][768][256]  (l0f, l0b, l1f, l1b)
#define OFF_X    3932160u    // x bf16 [8192][256] rows = t*128+b
#define OFF_XG   8126464u    // xg bf16 [2 dir][8192][768] planes (bias-fused; reused by both layers)
#define OFF_HIST 33292288u   // h0 history bf16 [8192][512] (f cols 0..255, b 256..511)
#define OFF_FS   41680896u   // final state fp32 [128][512]
#define OFF_BIAS 41943040u   // fp32 [2][1536] fused gemm bias (r,z: bih+bhh; n: bih)

static __device__ __forceinline__ usht f2bf(float f) {
  uint32_t x = __float_as_uint(f);
  uint32_t r = (x + 0x7fffu + ((x >> 16) & 1u)) >> 16;   // RNE
  return (usht)r;
}
static __device__ __forceinline__ float bf2f(usht u) {
  return __uint_as_float(((uint32_t)u) << 16);
}
static __device__ __forceinline__ void gload16(const void* g, void* l) {
  __builtin_amdgcn_global_load_lds((const __attribute__((address_space(1))) void*)g,
                                   (__attribute__((address_space(3))) void*)l, 16, 0, 0);
}

// ---------------- weight convert (fp32 -> bf16, padded/stacked) + fused bias build ----------------
__global__ __launch_bounds__(256) void prep_kernel(
    const float* s0, const float* s1, const float* s2, const float* s3,
    const float* s4, const float* s5, const float* s6, const float* s7,
    const float* bi0f, const float* bh0f, const float* bi0b, const float* bh0b,
    const float* bi1f, const float* bh1f, const float* bi1b, const float* bh1b,
    char* ws) {
  int job = blockIdx.y;
  int e = blockIdx.x * 256 + threadIdx.x;
  if (job == 8) {                               // fused bias: [2 layers][1536]
    if (e < 3072) {
      int L = e >= 1536 ? 1 : 0;
      int c = e - L * 1536;
      int d = c >= 768 ? 1 : 0;
      int cg = c - d * 768;
      int g = cg >> 8, u = cg & 255;
      const float* BI[4] = {bi0f, bi0b, bi1f, bi1b};
      const float* BH[4] = {bh0f, bh0b, bh1f, bh1b};
      int idx = L * 2 + d;
      float v = (g < 2) ? (BI[idx][g * 256 + u] + BH[idx][g * 256 + u]) : BI[idx][512 + u];
      ((float*)(ws + OFF_BIAS))[e] = v;
    }
    return;
  }
  const float* srcs[8] = {s0, s1, s2, s3, s4, s5, s6, s7};
  const int scols[8] = {200, 200, 512, 512, 256, 256, 256, 256};
  const int shf[8]   = {8, 8, 9, 9, 8, 8, 8, 8};
  const unsigned doff[8] = {0u, 196608u, 393216u, 786432u,
                            1179648u, 1376256u, 1572864u, 1769472u}; // usht elems
  int sh = shf[job];
  int dp = 1 << sh;
  if (e >= (768 << sh)) return;
  int row = e >> sh, col = e & (dp - 1);
  int sc = scols[job];
  float v = (col < sc) ? srcs[job][row * sc + col] : 0.f;
  ((usht*)ws)[doff[job] + (unsigned)e] = f2bf(v);
}

// ---------------- embedding gather with OOV mask -> bf16 [8192][256] ----------------
__global__ __launch_bounds__(256) void embed_kernel(
    const int* wi, const float* emb, const float* oove, usht* xb) {
  int tid = threadIdx.x;
  int rl = tid >> 5, c8 = tid & 31;
  int row = blockIdx.x * 8 + rl;          // 0..8191, row = t*128 + b
  int t = row >> 7, b = row & 127;
  int idx = wi[b * 64 + t];               // word_indices is [B=128][T=64]
  bool oov = (idx >= 100000);
  short8 v;
  if (c8 < 25) {                          // cols 0..199 (25*8 == 200)
    const float* src = oov ? (oove + c8 * 8) : (emb + (size_t)idx * 200 + c8 * 8);
#pragma unroll
    for (int e = 0; e < 8; ++e) v[e] = (short)f2bf(src[e]);
  } else {
#pragma unroll
    for (int e = 0; e < 8; ++e) v[e] = 0;
  }
  *(short8*)(xb + (size_t)row * 256 + c8 * 8) = v;
}

// ---------------- bf16 GEMM, B^T layout, fused bias, bf16 output into dir planes ----------------
// C_plane[dir][m][n'] = bf16( sum_k A[m][k]*Bw[n][k] + bias[n] ), n = dir*768 + n'
template<int KK>
__global__ __launch_bounds__(256) void gemm_bt(const usht* A, const usht* Bw,
                                               usht* Cx, const float* __restrict__ bias) {
  __shared__ usht sA[128 * 64];
  __shared__ usht sB[128 * 64];
  int tid = threadIdx.x;
  int w = tid >> 6, l = tid & 63, lc = l & 15, half = l >> 4;
  int wr = w >> 1, wc = w & 1;
  int gm0 = blockIdx.x * 128, gn0 = blockIdx.y * 128;
  f32x4 acc[4][4];
#pragma unroll
  for (int i = 0; i < 4; ++i)
#pragma unroll
    for (int j = 0; j < 4; ++j) acc[i][j] = (f32x4){0.f, 0.f, 0.f, 0.f};
  for (int ks = 0; ks < KK; ks += 64) {
#pragma unroll
    for (int it = 0; it < 4; ++it) {
      int qq = it * 4096 + tid * 16;      // byte offset within 16KB tile
      int row = qq >> 7;
      int cole = (qq & 127) >> 1;
      short8 va = *(const short8*)(A + (size_t)(gm0 + row) * KK + ks + cole);
      short8 vb = *(const short8*)(Bw + (size_t)(gn0 + row) * KK + ks + cole);
      *(short8*)(sA + (qq >> 1)) = va;
      *(short8*)(sB + (qq >> 1)) = vb;
    }
    __syncthreads();
#pragma unroll
    for (int kk = 0; kk < 2; ++kk) {
      short8 af[4], bq[4];
#pragma unroll
      for (int i = 0; i < 4; ++i)
        af[i] = *(const short8*)(sA + (wr * 64 + i * 16 + lc) * 64 + kk * 32 + half * 8);
#pragma unroll
      for (int j = 0; j < 4; ++j)
        bq[j] = *(const short8*)(sB + (wc * 64 + j * 16 + lc) * 64 + kk * 32 + half * 8);
#pragma unroll
      for (int i = 0; i < 4; ++i)
#pragma unroll
        for (int j = 0; j < 4; ++j)
          acc[i][j] = __builtin_amdgcn_mfma_f32_16x16x32_bf16(af[i], bq[j], acc[i][j], 0, 0, 0);
    }
    __syncthreads();
  }
#pragma unroll
  for (int j = 0; j < 4; ++j) {
    int col = gn0 + wc * 64 + j * 16 + lc;
    int dirc = col >= 768 ? 1 : 0;
    int ccol = col - dirc * 768;
    usht* base = Cx + (size_t)dirc * (8192 * 768);
    float bb = bias[col];
#pragma unroll
    for (int i = 0; i < 4; ++i)
#pragma unroll
      for (int r = 0; r < 4; ++r)
        base[(size_t)(gm0 + wr * 64 + i * 16 + half * 4 + r) * 768 + ccol] = f2bf(acc[i][j][r] + bb);
  }
}

// ---------------- recurrent scan: 16 WGs = 2 dir x 8 rowgroups(16 rows), 512 thr ----------------
// Full Whh per WG in 192 VGPR/lane; h exchange via LDS; xg staged via full-wave
// global_load_lds chunks, depth-3 prefetch (4 LDS buffers), counted vmcnt (T4),
// XOR-swizzled LDS tile (key ((r>>2)&3)<<4) applied source-side + read-side (rule #21).
template<int LAYER>
__global__ __launch_bounds__(512) void recur_kernel(
    const usht* __restrict__ xg, const usht* __restrict__ WhhL,
    const float* __restrict__ bhhf, const float* __restrict__ bhhb,
    usht* __restrict__ hist, float* __restrict__ fs) {
  extern __shared__ char smraw[];
  usht* xgb  = (usht*)smraw;               // 4 buffers x [16][768] shorts, swizzled (98304 B)
  usht* hbuf = (usht*)(smraw + 98304);     // 2 x [16][264] shorts (16896 B)
  int bid = blockIdx.x;
  int dir = bid & 1, rg = bid >> 1;
  int rowbase = rg * 16;
  int tid = threadIdx.x;
  int w = tid >> 6, l = tid & 63, lc = l & 15, q = l >> 4;
  int q8 = q << 3;                         // short-index swizzle key for own C/D rows
  int ub = w * 32;                         // wave owns units ub..ub+31
  const usht* xgp = xg + (size_t)dir * (8192 * 768);
  const usht* Wb = WhhL + (size_t)dir * (768 * 256);
  short8 bfrag[3][2][8];                   // 192 VGPR resident weights
#pragma unroll
  for (int g = 0; g < 3; ++g)
#pragma unroll
    for (int cc = 0; cc < 2; ++cc)
#pragma unroll
      for (int kt = 0; kt < 8; ++kt)
        bfrag[g][cc][kt] =
            *(const short8*)(Wb + (size_t)(g * 256 + ub + cc * 16 + lc) * 256 + kt * 32 + q * 8);
  const float* bhh = dir ? bhhb : bhhf;
  float bhhn0 = bhh[512 + ub + lc];
  float bhhn1 = bhh[512 + ub + 16 + lc];
  float hprev[2][4] = {{0.f, 0.f, 0.f, 0.f}, {0.f, 0.f, 0.f, 0.f}};

  // chunk geometry: per step, tile = 16 rows x 1536 B = 24 full-wave 1KB chunks; wave w owns 3.
  // lane's tile byte Lb = c*1024 + l*16; r = Lb/1536 via (Lb>>9)*171>>9; u = (Lb%1536)^key(r).
  int lb16 = l * 16;
#pragma unroll
  for (int p = 0; p < 3; ++p) {            // prologue: prefetch steps 0,1,2
    int ttp = dir ? 63 - p : p;
    const usht* slice = xgp + (size_t)(ttp * 128 + rowbase) * 768;
    char* bufb = (char*)(xgb + p * 12288);
#pragma unroll
    for (int k = 0; k < 3; ++k) {
      int c = w * 3 + k;
      int Lb = c * 1024 + lb16;
      int r = ((Lb >> 9) * 171) >> 9;
      int u = (Lb - r * 1536) ^ (((r >> 2) & 3) << 4);
      gload16(slice + r * 768 + (u >> 1), bufb + c * 1024);
    }
  }

  for (int s = 0; s < 64; ++s) {
    int tt = dir ? 63 - s : s;
    // prefetch step s+3 (full-wave chunks, uniform LDS dest, per-lane swizzled global src)
    {
      int sn = s + 3; if (sn > 63) sn = 63;
      int ttn = dir ? 63 - sn : sn;
      const usht* slice = xgp + (size_t)(ttn * 128 + rowbase) * 768;
      char* bufb = (char*)(xgb + ((s + 3) & 3) * 12288);
#pragma unroll
      for (int k = 0; k < 3; ++k) {
        int c = w * 3 + k;
        int Lb = c * 1024 + lb16;
        int r = ((Lb >> 9) * 171) >> 9;
        int u = (Lb - r * 1536) ^ (((r >> 2) & 3) << 4);
        gload16(slice + r * 768 + (u >> 1), bufb + c * 1024);
      }
    }
    // hidden MFMA phase: h_{s-1} @ Whh^T
    f32x4 acc[3][2];
#pragma unroll
    for (int g = 0; g < 3; ++g) {
      acc[g][0] = (f32x4){0.f, 0.f, 0.f, 0.f};
      acc[g][1] = (f32x4){0.f, 0.f, 0.f, 0.f};
    }
    if (s > 0) {
      const usht* hb = hbuf + ((s & 1) ^ 1) * 4224;
#pragma unroll
      for (int kt = 0; kt < 8; ++kt) {
        short8 afr = *(const short8*)(hb + lc * 264 + kt * 32 + q * 8);
#pragma unroll
        for (int g = 0; g < 3; ++g) {
          acc[g][0] = __builtin_amdgcn_mfma_f32_16x16x32_bf16(afr, bfrag[g][0][kt], acc[g][0], 0, 0, 0);
          acc[g][1] = __builtin_amdgcn_mfma_f32_16x16x32_bf16(afr, bfrag[g][1][kt], acc[g][1], 0, 0, 0);
        }
      }
    }
    // wait for step-s chunks: keep newer prefetches (and, L0, trailing stores) in flight.
    // LAYER0 steady state: newer-than-A(s) = B(s-3..s-1)=24 stores + A(s+1..s+3)=9 loads = 33.
    if (LAYER == 0) {
      if (s < 3) asm volatile("s_waitcnt vmcnt(9)\ns_barrier" ::: "memory");
      else       asm volatile("s_waitcnt vmcnt(33)\ns_barrier" ::: "memory");
    } else {
      asm volatile("s_waitcnt vmcnt(9)\ns_barrier" ::: "memory");
    }
    // gate phase
    const usht* xb_s = xgb + (s & 3) * 12288;
    usht* hw = hbuf + (s & 1) * 4224;
#pragma unroll
    for (int cc = 0; cc < 2; ++cc) {
      int j = ub + cc * 16 + lc;
      float bn = cc ? bhhn1 : bhhn0;
#pragma unroll
      for (int i = 0; i < 4; ++i) {
        int rr = q * 4 + i;                          // own batch row (C/D layout)
        const usht* xrow = xb_s + rr * 768;
        float xv_r = bf2f(xrow[(j) ^ q8]);
        float xv_z = bf2f(xrow[(256 + j) ^ q8]);
        float xv_n = bf2f(xrow[(512 + j) ^ q8]);
        float rg_ = 1.f / (1.f + __expf(-(xv_r + acc[0][cc][i])));
        float zg_ = 1.f / (1.f + __expf(-(xv_z + acc[1][cc][i])));
        float pn = xv_n + rg_ * (acc[2][cc][i] + bn);
        float nn = 2.f / (1.f + __expf(-2.f * pn)) - 1.f;   // tanh
        float hv = (1.f - zg_) * nn + zg_ * hprev[cc][i];
        hprev[cc][i] = hv;
        usht hb16 = f2bf(hv);
        hw[rr * 264 + j] = hb16;
        if (LAYER == 0)
          hist[((size_t)(tt * 128 + rowbase + rr)) * 512 + dir * 256 + j] = hb16;
        if (LAYER == 1) {
          if (s == 63) fs[(size_t)(rowbase + rr) * 512 + dir * 256 + j] = hv;
        }
      }
    }
    // h_s LDS writes visible before next iter's MFMA reads
    asm volatile("s_waitcnt lgkmcnt(0)\ns_barrier" ::: "memory");
  }
}

// ---------------- final projection: out[b][o] = fs[b][:] . proj_W[o][:] + pb[o] ----------------
__global__ __launch_bounds__(256) void proj_kernel(const float* fs, const float* pW,
                                                   const float* pb, float* out) {
  __shared__ float sf[512];
  int b = blockIdx.x, o = threadIdx.x;
  for (int k = o; k < 512; k += 256) sf[k] = fs[b * 512 + k];
  __syncthreads();
  const float* wr_ = pW + (size_t)o * 512;
  float s = 0.f;
#pragma unroll 4
  for (int k = 0; k < 512; k += 4) {
    float4 wv = *(const float4*)(wr_ + k);
    s += wv.x * sf[k] + wv.y * sf[k + 1] + wv.z * sf[k + 2] + wv.w * sf[k + 3];
  }
  out[(size_t)b * 256 + o] = s + pb[o];
}

extern "C" void kernel_launch(void* const* d_in, const int* in_sizes, int n_in,
                              void* d_out, int out_size, void* d_ws, size_t ws_size,
                              hipStream_t stream) {
  const int*   wi    = (const int*)d_in[0];
  const float* emb   = (const float*)d_in[1];
  const float* oove  = (const float*)d_in[2];
  const float* Wih0f = (const float*)d_in[3];
  const float* Whh0f = (const float*)d_in[4];
  const float* bih0f = (const float*)d_in[5];
  const float* bhh0f = (const float*)d_in[6];
  const float* Wih0b = (const float*)d_in[7];
  const float* Whh0b = (const float*)d_in[8];
  const float* bih0b = (const float*)d_in[9];
  const float* bhh0b = (const float*)d_in[10];
  const float* Wih1f = (const float*)d_in[11];
  const float* Whh1f = (const float*)d_in[12];
  const float* bih1f = (const float*)d_in[13];
  const float* bhh1f = (const float*)d_in[14];
  const float* Wih1b = (const float*)d_in[15];
  const float* Whh1b = (const float*)d_in[16];
  const float* bih1b = (const float*)d_in[17];
  const float* bhh1b = (const float*)d_in[18];
  const float* projW = (const float*)d_in[19];
  const float* projb = (const float*)d_in[20];

  char* ws = (char*)d_ws;
  usht*  w0   = (usht*)(ws + OFF_W0);
  usht*  w1   = (usht*)(ws + OFF_W1);
  usht*  whh  = (usht*)(ws + OFF_WHH);
  usht*  xb   = (usht*)(ws + OFF_X);
  usht*  xg   = (usht*)(ws + OFF_XG);
  usht*  hist = (usht*)(ws + OFF_HIST);
  float* fs   = (float*)(ws + OFF_FS);
  float* bias = (float*)(ws + OFF_BIAS);

  prep_kernel<<<dim3(1536, 9), 256, 0, stream>>>(
      Wih0f, Wih0b, Wih1f, Wih1b, Whh0f, Whh0b, Whh1f, Whh1b,
      bih0f, bhh0f, bih0b, bhh0b, bih1f, bhh1f, bih1b, bhh1b, ws);
  embed_kernel<<<1024, 256, 0, stream>>>(wi, emb, oove, xb);
  gemm_bt<256><<<dim3(64, 12), 256, 0, stream>>>(xb, w0, xg, bias);
  recur_kernel<0><<<16, 512, 115200, stream>>>(xg, whh, bhh0f, bhh0b, hist, fs);
  gemm_bt<512><<<dim3(64, 12), 256, 0, stream>>>(hist, w1, xg, bias + 1536);
  recur_kernel<1><<<16, 512, 115200, stream>>>(xg, whh + 2 * 768 * 256, bhh1f, bhh1b, hist, fs);
  proj_kernel<<<128, 256, 0, stream>>>(fs, projW, projb, (float*)d_out);
}

// Round 8
// 570.288 us; speedup vs baseline: 2.6447x; 1.2041x over previous
//
#include <hip/hip_runtime.h>
#include <hip/hip_bf16.h>
#include <stdint.h>

typedef __attribute__((ext_vector_type(8))) short short8;   // 8 bf16 (4 VGPRs)
typedef __attribute__((ext_vector_type(4))) float f32x4;    // 4 fp32
typedef unsigned short usht;

// ---- workspace byte offsets ----
#define OFF_W0   0u          // W0cat bf16 [1536][256]  (Wih0f 0..767, Wih0b 768..1535; K pad 200->256)
#define OFF_W1   786432u     // W1cat bf16 [1536][512]
#define OFF_WHH  2359296u    // Whh FP8 e4m3 [4][768][256] bytes (l0f, l0b, l1f, l1b)
#define OFF_X    3145728u    // x bf16 [8192][256] rows = t*128+b
#define OFF_XGP  7340032u    // xg bf16 packed [2 dir][8192 row][256 unit][4] (g=r,z,n,pad; bias-fused)
#define OFF_HIST 40894464u   // h0 history bf16 [8192][512] (f cols 0..255, b 256..511)
#define OFF_FS   49283072u   // final state fp32 [128][512]
#define OFF_BIAS 49545216u   // fp32 [2][1536] fused gemm bias (r,z: bih+bhh; n: bih)

static __device__ __forceinline__ usht f2bf(float f) {
  uint32_t x = __float_as_uint(f);
  uint32_t r = (x + 0x7fffu + ((x >> 16) & 1u)) >> 16;   // RNE
  return (usht)r;
}
static __device__ __forceinline__ float bf2f(usht u) {
  return __uint_as_float(((uint32_t)u) << 16);
}
// f32 -> fp8 e4m3fn (OCP), RNE, with denormal support and clamp to 448
static __device__ __forceinline__ unsigned char f2fp8(float x) {
#if __has_builtin(__builtin_amdgcn_cvt_pk_fp8_f32)
  return (unsigned char)(__builtin_amdgcn_cvt_pk_fp8_f32(x, x, 0, false) & 0xff);
#else
  uint32_t u = __float_as_uint(x);
  uint32_t s8 = (u >> 24) & 0x80u;
  float ax = fabsf(x);
  if (ax >= 448.f) return (unsigned char)(s8 | 0x7Eu);
  if (ax < 0.015625f) {                       // denormal: units of 2^-9
    int m = (int)(ax * 512.f + 0.5f);
    return (unsigned char)(s8 | (uint32_t)m);
  }
  uint32_t au = u & 0x7FFFFFFFu;
  uint32_t r = au + 0x7FFFFu + ((au >> 20) & 1u);
  int e = (int)(r >> 23) - 127 + 7;
  if (e >= 16) return (unsigned char)(s8 | 0x7Eu);
  return (unsigned char)(s8 | ((uint32_t)e << 3) | ((r >> 20) & 7u));
#endif
}

// ---------------- weight convert (bf16 Wih, FP8 Whh) + fused bias build ----------------
__global__ __launch_bounds__(256) void prep_kernel(
    const float* s0, const float* s1, const float* s2, const float* s3,
    const float* s4, const float* s5, const float* s6, const float* s7,
    const float* bi0f, const float* bh0f, const float* bi0b, const float* bh0b,
    const float* bi1f, const float* bh1f, const float* bi1b, const float* bh1b,
    char* ws) {
  int job = blockIdx.y;
  int e = blockIdx.x * 256 + threadIdx.x;
  if (job == 8) {                               // fused bias: [2 layers][1536]
    if (e < 3072) {
      int L = e >= 1536 ? 1 : 0;
      int c = e - L * 1536;
      int d = c >= 768 ? 1 : 0;
      int cg = c - d * 768;
      int g = cg >> 8, u = cg & 255;
      const float* BI[4] = {bi0f, bi0b, bi1f, bi1b};
      const float* BH[4] = {bh0f, bh0b, bh1f, bh1b};
      int idx = L * 2 + d;
      float v = (g < 2) ? (BI[idx][g * 256 + u] + BH[idx][g * 256 + u]) : BI[idx][512 + u];
      ((float*)(ws + OFF_BIAS))[e] = v;
    }
    return;
  }
  if (job >= 4) {                               // Whh -> fp8 e4m3, [768][256] each
    const float* srcs[4] = {s4, s5, s6, s7};
    if (e >= 768 * 256) return;
    float v = srcs[job - 4][e];
    ((unsigned char*)ws)[OFF_WHH + (unsigned)(job - 4) * 196608u + (unsigned)e] = f2fp8(v);
    return;
  }
  const float* srcs[4] = {s0, s1, s2, s3};      // Wih -> bf16 padded/stacked
  const int scols[4] = {200, 200, 512, 512};
  const int shf[4]   = {8, 8, 9, 9};
  const unsigned doff[4] = {0u, 196608u, 393216u, 786432u};  // usht elems
  int sh = shf[job];
  int dp = 1 << sh;
  if (e >= (768 << sh)) return;
  int row = e >> sh, col = e & (dp - 1);
  int sc = scols[job];
  float v = (col < sc) ? srcs[job][row * sc + col] : 0.f;
  ((usht*)ws)[doff[job] + (unsigned)e] = f2bf(v);
}

// ---------------- embedding gather with OOV mask -> bf16 [8192][256] ----------------
__global__ __launch_bounds__(256) void embed_kernel(
    const int* wi, const float* emb, const float* oove, usht* xb) {
  int tid = threadIdx.x;
  int rl = tid >> 5, c8 = tid & 31;
  int row = blockIdx.x * 8 + rl;          // 0..8191, row = t*128 + b
  int t = row >> 7, b = row & 127;
  int idx = wi[b * 64 + t];               // word_indices is [B=128][T=64]
  bool oov = (idx >= 100000);
  short8 v;
  if (c8 < 25) {                          // cols 0..199 (25*8 == 200)
    const float* src = oov ? (oove + c8 * 8) : (emb + (size_t)idx * 200 + c8 * 8);
#pragma unroll
    for (int e = 0; e < 8; ++e) v[e] = (short)f2bf(src[e]);
  } else {
#pragma unroll
    for (int e = 0; e < 8; ++e) v[e] = 0;
  }
  *(short8*)(xb + (size_t)row * 256 + c8 * 8) = v;
}

// ---------------- bf16 GEMM, B^T layout, fused bias, packed bf16 output ----------------
// out[dir][row][unit][4]: slot g<-{r,z,n}; pad slot unused. n = dir*768 + g*256 + u.
template<int KK>
__global__ __launch_bounds__(256) void gemm_bt(const usht* A, const usht* Bw,
                                               usht* Cx, const float* __restrict__ bias) {
  __shared__ usht sA[128 * 64];
  __shared__ usht sB[128 * 64];
  int tid = threadIdx.x;
  int w = tid >> 6, l = tid & 63, lc = l & 15, half = l >> 4;
  int wr = w >> 1, wc = w & 1;
  int gm0 = blockIdx.x * 128, gn0 = blockIdx.y * 128;
  f32x4 acc[4][4];
#pragma unroll
  for (int i = 0; i < 4; ++i)
#pragma unroll
    for (int j = 0; j < 4; ++j) acc[i][j] = (f32x4){0.f, 0.f, 0.f, 0.f};
  for (int ks = 0; ks < KK; ks += 64) {
#pragma unroll
    for (int it = 0; it < 4; ++it) {
      int qq = it * 4096 + tid * 16;      // byte offset within 16KB tile
      int row = qq >> 7;
      int cole = (qq & 127) >> 1;
      short8 va = *(const short8*)(A + (size_t)(gm0 + row) * KK + ks + cole);
      short8 vb = *(const short8*)(Bw + (size_t)(gn0 + row) * KK + ks + cole);
      *(short8*)(sA + (qq >> 1)) = va;
      *(short8*)(sB + (qq >> 1)) = vb;
    }
    __syncthreads();
#pragma unroll
    for (int kk = 0; kk < 2; ++kk) {
      short8 af[4], bq[4];
#pragma unroll
      for (int i = 0; i < 4; ++i)
        af[i] = *(const short8*)(sA + (wr * 64 + i * 16 + lc) * 64 + kk * 32 + half * 8);
#pragma unroll
      for (int j = 0; j < 4; ++j)
        bq[j] = *(const short8*)(sB + (wc * 64 + j * 16 + lc) * 64 + kk * 32 + half * 8);
#pragma unroll
      for (int i = 0; i < 4; ++i)
#pragma unroll
        for (int j = 0; j < 4; ++j)
          acc[i][j] = __builtin_amdgcn_mfma_f32_16x16x32_bf16(af[i], bq[j], acc[i][j], 0, 0, 0);
    }
    __syncthreads();
  }
#pragma unroll
  for (int j = 0; j < 4; ++j) {
    int col = gn0 + wc * 64 + j * 16 + lc;
    int dirc = col >= 768 ? 1 : 0;
    int cg = col - dirc * 768;
    int g = cg >> 8, u = cg & 255;
    usht* base = Cx + (size_t)dirc * 8388608u;   // plane stride in shorts
    float bb = bias[col];
#pragma unroll
    for (int i = 0; i < 4; ++i)
#pragma unroll
      for (int r = 0; r < 4; ++r) {
        int row = gm0 + wr * 64 + i * 16 + half * 4 + r;
        base[(size_t)row * 1024 + u * 4 + g] = f2bf(acc[i][j][r] + bb);
      }
  }
}

// ---------------- recurrent scan: 16 WGs = 2 dir x 8 rowgroups(16 rows), 512 thr ----------------
// Whh resident as FP8 B-frags (96 VGPR/lane); h exchanged via tiny fp8 LDS buffer;
// xg loaded to REGISTERS (packed ushort4), depth-3 ring over 4 static slots (unroll-4);
// compiler inserts exact vmcnt for reg loads; ONE barrier per step.
template<int LAYER>
__global__ __launch_bounds__(512, 2) void recur_kernel(
    const usht* __restrict__ xgp, const unsigned char* __restrict__ WhhL,
    const float* __restrict__ bhhf, const float* __restrict__ bhhb,
    usht* __restrict__ hist, float* __restrict__ fs) {
  __shared__ unsigned char hbuf[2 * 16 * 272];   // fp8 h, row stride 272 B
  int bid = blockIdx.x;
  int dir = bid & 1, rg = bid >> 1;
  int rowbase = rg * 16;
  int tid = threadIdx.x;
  int w = tid >> 6, l = tid & 63, lc = l & 15, q = l >> 4;
  int ub = w * 32;                               // wave owns units ub..ub+31
  const unsigned char* Wb = WhhL + (size_t)dir * 196608u;
  long bfrag[3][2][8];                           // fp8 B-frags: 96 VGPRs, resident
#pragma unroll
  for (int g = 0; g < 3; ++g)
#pragma unroll
    for (int cc = 0; cc < 2; ++cc)
#pragma unroll
      for (int kt = 0; kt < 8; ++kt)
        bfrag[g][cc][kt] =
            *(const long*)(Wb + (size_t)(g * 256 + ub + cc * 16 + lc) * 256 + kt * 32 + q * 8);
  const float* bhh = dir ? bhhb : bhhf;
  float bhhn0 = bhh[512 + ub + lc];
  float bhhn1 = bhh[512 + ub + 16 + lc];
  float hprev[2][4] = {{0.f, 0.f, 0.f, 0.f}, {0.f, 0.f, 0.f, 0.f}};
  const usht* xp = xgp + (size_t)dir * 8388608u;
  int xoff[8];                                   // short offsets, per (cc,i)
#pragma unroll
  for (int cc = 0; cc < 2; ++cc)
#pragma unroll
    for (int i = 0; i < 4; ++i)
      xoff[cc * 4 + i] = (rowbase + q * 4 + i) * 1024 + (ub + cc * 16 + lc) * 4;

  ushort4 xs0[8], xs1[8], xs2[8], xs3[8];        // 4 static slots (rule #20)
  {                                              // prologue: prefetch steps 0,1,2
    int t0 = dir ? 63 : 0, t1 = dir ? 62 : 1, t2 = dir ? 61 : 2;
#pragma unroll
    for (int k = 0; k < 8; ++k) xs0[k] = *(const ushort4*)(xp + t0 * 131072 + xoff[k]);
#pragma unroll
    for (int k = 0; k < 8; ++k) xs1[k] = *(const ushort4*)(xp + t1 * 131072 + xoff[k]);
#pragma unroll
    for (int k = 0; k < 8; ++k) xs2[k] = *(const ushort4*)(xp + t2 * 131072 + xoff[k]);
  }
  const f32x4 zf4 = (f32x4){0.f, 0.f, 0.f, 0.f};

#define BODY(J, XC, XN)                                                              \
  {                                                                                  \
    const int s = it4 + (J);                                                         \
    const int tt = dir ? 63 - s : s;                                                 \
    {                                                                                \
      int sn = s + 3; if (sn > 63) sn = 63;                                          \
      int ttn = dir ? 63 - sn : sn;                                                  \
      const usht* pb = xp + ttn * 131072;                                            \
      _Pragma("unroll")                                                              \
      for (int k = 0; k < 8; ++k) XN[k] = *(const ushort4*)(pb + xoff[k]);           \
    }                                                                                \
    f32x4 acc[3][2];                                                                 \
    _Pragma("unroll")                                                                \
    for (int g = 0; g < 3; ++g) { acc[g][0] = zf4; acc[g][1] = zf4; }                \
    if ((J) != 0 || it4 != 0) {                                                      \
      const unsigned char* hb = hbuf + (((s & 1) ^ 1) * 4352);                       \
      _Pragma("unroll")                                                              \
      for (int kt = 0; kt < 8; ++kt) {                                               \
        long a = *(const long*)(hb + lc * 272 + kt * 32 + q * 8);                    \
        _Pragma("unroll")                                                            \
        for (int g = 0; g < 3; ++g) {                                                \
          acc[g][0] = __builtin_amdgcn_mfma_f32_16x16x32_fp8_fp8(a, bfrag[g][0][kt], acc[g][0], 0, 0, 0); \
          acc[g][1] = __builtin_amdgcn_mfma_f32_16x16x32_fp8_fp8(a, bfrag[g][1][kt], acc[g][1], 0, 0, 0); \
        }                                                                            \
      }                                                                              \
    }                                                                                \
    unsigned char* hw = hbuf + ((s & 1) * 4352);                                     \
    _Pragma("unroll")                                                                \
    for (int cc = 0; cc < 2; ++cc) {                                                 \
      int jj = ub + cc * 16 + lc;                                                    \
      float bn = cc ? bhhn1 : bhhn0;                                                 \
      _Pragma("unroll")                                                              \
      for (int i = 0; i < 4; ++i) {                                                  \
        int rr = q * 4 + i;                                                          \
        ushort4 xv = XC[cc * 4 + i];                                                 \
        float xr_ = bf2f(xv.x), xz_ = bf2f(xv.y), xn_ = bf2f(xv.z);                  \
        float rg_ = 1.f / (1.f + __expf(-(xr_ + acc[0][cc][i])));                    \
        float zg_ = 1.f / (1.f + __expf(-(xz_ + acc[1][cc][i])));                    \
        float pn = xn_ + rg_ * (acc[2][cc][i] + bn);                                 \
        float nn = 2.f / (1.f + __expf(-2.f * pn)) - 1.f;                            \
        float hv = (1.f - zg_) * nn + zg_ * hprev[cc][i];                            \
        hprev[cc][i] = hv;                                                           \
        hw[rr * 272 + jj] = f2fp8(hv);                                               \
        if (LAYER == 0)                                                              \
          hist[((size_t)(tt * 128 + rowbase + rr)) * 512 + dir * 256 + jj] = f2bf(hv); \
        if (LAYER == 1 && (J) == 3 && it4 == 60)                                     \
          fs[(size_t)(rowbase + rr) * 512 + dir * 256 + jj] = hv;                    \
      }                                                                              \
    }                                                                                \
    asm volatile("s_waitcnt lgkmcnt(0)\ns_barrier" ::: "memory");                    \
  }

#pragma unroll 1
  for (int it = 0; it < 16; ++it) {
    int it4 = it * 4;
    BODY(0, xs0, xs3)
    BODY(1, xs1, xs0)
    BODY(2, xs2, xs1)
    BODY(3, xs3, xs2)
  }
#undef BODY
}

// ---------------- final projection: out[b][o] = fs[b][:] . proj_W[o][:] + pb[o] ----------------
__global__ __launch_bounds__(256) void proj_kernel(const float* fs, const float* pW,
                                                   const float* pb, float* out) {
  __shared__ float sf[512];
  int b = blockIdx.x, o = threadIdx.x;
  for (int k = o; k < 512; k += 256) sf[k] = fs[b * 512 + k];
  __syncthreads();
  const float* wr_ = pW + (size_t)o * 512;
  float s = 0.f;
#pragma unroll 4
  for (int k = 0; k < 512; k += 4) {
    float4 wv = *(const float4*)(wr_ + k);
    s += wv.x * sf[k] + wv.y * sf[k + 1] + wv.z * sf[k + 2] + wv.w * sf[k + 3];
  }
  out[(size_t)b * 256 + o] = s + pb[o];
}

extern "C" void kernel_launch(void* const* d_in, const int* in_sizes, int n_in,
                              void* d_out, int out_size, void* d_ws, size_t ws_size,
                              hipStream_t stream) {
  const int*   wi    = (const int*)d_in[0];
  const float* emb   = (const float*)d_in[1];
  const float* oove  = (const float*)d_in[2];
  const float* Wih0f = (const float*)d_in[3];
  const float* Whh0f = (const float*)d_in[4];
  const float* bih0f = (const float*)d_in[5];
  const float* bhh0f = (const float*)d_in[6];
  const float* Wih0b = (const float*)d_in[7];
  const float* Whh0b = (const float*)d_in[8];
  const float* bih0b = (const float*)d_in[9];
  const float* bhh0b = (const float*)d_in[10];
  const float* Wih1f = (const float*)d_in[11];
  const float* Whh1f = (const float*)d_in[12];
  const float* bih1f = (const float*)d_in[13];
  const float* bhh1f = (const float*)d_in[14];
  const float* Wih1b = (const float*)d_in[15];
  const float* Whh1b = (const float*)d_in[16];
  const float* bih1b = (const float*)d_in[17];
  const float* bhh1b = (const float*)d_in[18];
  const float* projW = (const float*)d_in[19];
  const float* projb = (const float*)d_in[20];

  char* ws = (char*)d_ws;
  usht*  w0   = (usht*)(ws + OFF_W0);
  usht*  w1   = (usht*)(ws + OFF_W1);
  unsigned char* whh = (unsigned char*)(ws + OFF_WHH);
  usht*  xb   = (usht*)(ws + OFF_X);
  usht*  xgp  = (usht*)(ws + OFF_XGP);
  usht*  hist = (usht*)(ws + OFF_HIST);
  float* fs   = (float*)(ws + OFF_FS);
  float* bias = (float*)(ws + OFF_BIAS);

  prep_kernel<<<dim3(1536, 9), 256, 0, stream>>>(
      Wih0f, Wih0b, Wih1f, Wih1b, Whh0f, Whh0b, Whh1f, Whh1b,
      bih0f, bhh0f, bih0b, bhh0b, bih1f, bhh1f, bih1b, bhh1b, ws);
  embed_kernel<<<1024, 256, 0, stream>>>(wi, emb, oove, xb);
  gemm_bt<256><<<dim3(64, 12), 256, 0, stream>>>(xb, w0, xgp, bias);
  recur_kernel<0><<<16, 512, 0, stream>>>(xgp, whh, bhh0f, bhh0b, hist, fs);
  gemm_bt<512><<<dim3(64, 12), 256, 0, stream>>>(hist, w1, xgp, bias + 1536);
  recur_kernel<1><<<16, 512, 0, stream>>>(xgp, whh + 2 * 196608, bhh1f, bhh1b, hist, fs);
  proj_kernel<<<128, 256, 0, stream>>>(fs, projW, projb, (float*)d_out);
}

// Round 9
// 392.612 us; speedup vs baseline: 3.8415x; 1.4525x over previous
//
#include <hip/hip_runtime.h>
#include <hip/hip_bf16.h>
#include <stdint.h>

typedef __attribute__((ext_vector_type(8))) short short8;   // 8 bf16 (4 VGPRs)
typedef __attribute__((ext_vector_type(4))) float f32x4;    // 4 fp32
typedef unsigned short usht;

// ---- workspace byte offsets ----
#define OFF_W0   0u          // W0cat bf16 [1536][256]  (Wih0f 0..767, Wih0b 768..1535; K pad 200->256)
#define OFF_W1   786432u     // W1cat bf16 [1536][512]
#define OFF_WHH  2359296u    // Whh FP8 e4m3 [4][768][256] bytes (l0f, l0b, l1f, l1b)
#define OFF_X    3145728u    // x bf16 [8192][256] rows = t*128+b
#define OFF_XGP  7340032u    // xg bf16 packed [2 dir][8192 row][256 unit][4] (g=r,z,n,pad; bias-fused)
#define OFF_HIST 40894464u   // h0 history bf16 [8192][512] (f cols 0..255, b 256..511)
#define OFF_FS   49283072u   // final state fp32 [128][512]
#define OFF_BIAS 49545216u   // fp32 [2][1536] fused gemm bias (r,z: bih+bhh; n: bih)

static __device__ __forceinline__ usht f2bf(float f) {
  uint32_t x = __float_as_uint(f);
  uint32_t r = (x + 0x7fffu + ((x >> 16) & 1u)) >> 16;   // RNE
  return (usht)r;
}
static __device__ __forceinline__ float bf2f(usht u) {
  return __uint_as_float(((uint32_t)u) << 16);
}
// f32 -> fp8 e4m3fn (OCP), RNE, with denormal support and clamp to 448
static __device__ __forceinline__ unsigned char f2fp8(float x) {
#if __has_builtin(__builtin_amdgcn_cvt_pk_fp8_f32)
  return (unsigned char)(__builtin_amdgcn_cvt_pk_fp8_f32(x, x, 0, false) & 0xff);
#else
  uint32_t u = __float_as_uint(x);
  uint32_t s8 = (u >> 24) & 0x80u;
  float ax = fabsf(x);
  if (ax >= 448.f) return (unsigned char)(s8 | 0x7Eu);
  if (ax < 0.015625f) {                       // denormal: units of 2^-9
    int m = (int)(ax * 512.f + 0.5f);
    return (unsigned char)(s8 | (uint32_t)m);
  }
  uint32_t au = u & 0x7FFFFFFFu;
  uint32_t r = au + 0x7FFFFu + ((au >> 20) & 1u);
  int e = (int)(r >> 23) - 127 + 7;
  if (e >= 16) return (unsigned char)(s8 | 0x7Eu);
  return (unsigned char)(s8 | ((uint32_t)e << 3) | ((r >> 20) & 7u));
#endif
}
// fast sigmoid / tanh via v_exp_f32 (=2^x) + v_rcp_f32
static __device__ __forceinline__ float fsig(float x) {
  float e, r;
  asm("v_exp_f32 %0, %1" : "=v"(e) : "v"(x * -1.44269504f));
  asm("v_rcp_f32 %0, %1" : "=v"(r) : "v"(1.f + e));
  return r;
}
static __device__ __forceinline__ float ftanh(float x) {
  float e, r;
  asm("v_exp_f32 %0, %1" : "=v"(e) : "v"(x * -2.88539008f));
  asm("v_rcp_f32 %0, %1" : "=v"(r) : "v"(1.f + e));
  return fmaf(2.f, r, -1.f);
}

// ---------------- weight convert (bf16 Wih, FP8 Whh) + fused bias build ----------------
__global__ __launch_bounds__(256) void prep_kernel(
    const float* s0, const float* s1, const float* s2, const float* s3,
    const float* s4, const float* s5, const float* s6, const float* s7,
    const float* bi0f, const float* bh0f, const float* bi0b, const float* bh0b,
    const float* bi1f, const float* bh1f, const float* bi1b, const float* bh1b,
    char* ws) {
  int job = blockIdx.y;
  int e = blockIdx.x * 256 + threadIdx.x;
  if (job == 8) {                               // fused bias: [2 layers][1536]
    if (e < 3072) {
      int L = e >= 1536 ? 1 : 0;
      int c = e - L * 1536;
      int d = c >= 768 ? 1 : 0;
      int cg = c - d * 768;
      int g = cg >> 8, u = cg & 255;
      const float* BI[4] = {bi0f, bi0b, bi1f, bi1b};
      const float* BH[4] = {bh0f, bh0b, bh1f, bh1b};
      int idx = L * 2 + d;
      float v = (g < 2) ? (BI[idx][g * 256 + u] + BH[idx][g * 256 + u]) : BI[idx][512 + u];
      ((float*)(ws + OFF_BIAS))[e] = v;
    }
    return;
  }
  if (job >= 4) {                               // Whh -> fp8 e4m3, [768][256] each
    const float* srcs[4] = {s4, s5, s6, s7};
    if (e >= 768 * 256) return;
    float v = srcs[job - 4][e];
    ((unsigned char*)ws)[OFF_WHH + (unsigned)(job - 4) * 196608u + (unsigned)e] = f2fp8(v);
    return;
  }
  const float* srcs[4] = {s0, s1, s2, s3};      // Wih -> bf16 padded/stacked
  const int scols[4] = {200, 200, 512, 512};
  const int shf[4]   = {8, 8, 9, 9};
  const unsigned doff[4] = {0u, 196608u, 393216u, 786432u};  // usht elems
  int sh = shf[job];
  int dp = 1 << sh;
  if (e >= (768 << sh)) return;
  int row = e >> sh, col = e & (dp - 1);
  int sc = scols[job];
  float v = (col < sc) ? srcs[job][row * sc + col] : 0.f;
  ((usht*)ws)[doff[job] + (unsigned)e] = f2bf(v);
}

// ---------------- embedding gather with OOV mask -> bf16 [8192][256] ----------------
__global__ __launch_bounds__(256) void embed_kernel(
    const int* wi, const float* emb, const float* oove, usht* xb) {
  int tid = threadIdx.x;
  int rl = tid >> 5, c8 = tid & 31;
  int row = blockIdx.x * 8 + rl;          // 0..8191, row = t*128 + b
  int t = row >> 7, b = row & 127;
  int idx = wi[b * 64 + t];               // word_indices is [B=128][T=64]
  bool oov = (idx >= 100000);
  short8 v;
  if (c8 < 25) {                          // cols 0..199 (25*8 == 200)
    const float* src = oov ? (oove + c8 * 8) : (emb + (size_t)idx * 200 + c8 * 8);
#pragma unroll
    for (int e = 0; e < 8; ++e) v[e] = (short)f2bf(src[e]);
  } else {
#pragma unroll
    for (int e = 0; e < 8; ++e) v[e] = 0;
  }
  *(short8*)(xb + (size_t)row * 256 + c8 * 8) = v;
}

// ---------------- bf16 GEMM, B^T layout, fused bias, packed bf16 output ----------------
// out[dir][row][unit][4]: slot g<-{r,z,n}; pad slot unused. n = dir*768 + g*256 + u.
template<int KK>
__global__ __launch_bounds__(256) void gemm_bt(const usht* A, const usht* Bw,
                                               usht* Cx, const float* __restrict__ bias) {
  __shared__ usht sA[128 * 64];
  __shared__ usht sB[128 * 64];
  int tid = threadIdx.x;
  int w = tid >> 6, l = tid & 63, lc = l & 15, half = l >> 4;
  int wr = w >> 1, wc = w & 1;
  int gm0 = blockIdx.x * 128, gn0 = blockIdx.y * 128;
  f32x4 acc[4][4];
#pragma unroll
  for (int i = 0; i < 4; ++i)
#pragma unroll
    for (int j = 0; j < 4; ++j) acc[i][j] = (f32x4){0.f, 0.f, 0.f, 0.f};
  for (int ks = 0; ks < KK; ks += 64) {
#pragma unroll
    for (int it = 0; it < 4; ++it) {
      int qq = it * 4096 + tid * 16;      // byte offset within 16KB tile
      int row = qq >> 7;
      int cole = (qq & 127) >> 1;
      short8 va = *(const short8*)(A + (size_t)(gm0 + row) * KK + ks + cole);
      short8 vb = *(const short8*)(Bw + (size_t)(gn0 + row) * KK + ks + cole);
      *(short8*)(sA + (qq >> 1)) = va;
      *(short8*)(sB + (qq >> 1)) = vb;
    }
    __syncthreads();
#pragma unroll
    for (int kk = 0; kk < 2; ++kk) {
      short8 af[4], bq[4];
#pragma unroll
      for (int i = 0; i < 4; ++i)
        af[i] = *(const short8*)(sA + (wr * 64 + i * 16 + lc) * 64 + kk * 32 + half * 8);
#pragma unroll
      for (int j = 0; j < 4; ++j)
        bq[j] = *(const short8*)(sB + (wc * 64 + j * 16 + lc) * 64 + kk * 32 + half * 8);
#pragma unroll
      for (int i = 0; i < 4; ++i)
#pragma unroll
        for (int j = 0; j < 4; ++j)
          acc[i][j] = __builtin_amdgcn_mfma_f32_16x16x32_bf16(af[i], bq[j], acc[i][j], 0, 0, 0);
    }
    __syncthreads();
  }
#pragma unroll
  for (int j = 0; j < 4; ++j) {
    int col = gn0 + wc * 64 + j * 16 + lc;
    int dirc = col >= 768 ? 1 : 0;
    int cg = col - dirc * 768;
    int g = cg >> 8, u = cg & 255;
    usht* base = Cx + (size_t)dirc * 8388608u;   // plane stride in shorts
    float bb = bias[col];
#pragma unroll
    for (int i = 0; i < 4; ++i)
#pragma unroll
      for (int r = 0; r < 4; ++r) {
        int row = gm0 + wr * 64 + i * 16 + half * 4 + r;
        base[(size_t)row * 1024 + u * 4 + g] = f2bf(acc[i][j][r] + bb);
      }
  }
}

// ---------------- recurrent scan: 32 WGs = 2 dir x 16 rowgroups(8 rows), 512 thr ----------------
// Row-duplication trick: MFMA A-frag loads each of the 8 rows twice (row = lc&7), so
// every (row,unit) C/D cell exists on TWO q-groups; assign cc=q>>1, row-half=q&1 ->
// 4 gate cells/lane (halves gate VALU per CU, doubles CU count vs 16-row WGs).
// Whh resident as FP8 B-frags (96 VGPR/lane); h via tiny fp8 LDS; xg in registers
// (depth-3 ring over 4 static slots); fast sigmoid/tanh (v_exp+v_rcp).
template<int LAYER>
__global__ __launch_bounds__(512, 2) void recur_kernel(
    const usht* __restrict__ xgp, const unsigned char* __restrict__ WhhL,
    const float* __restrict__ bhhf, const float* __restrict__ bhhb,
    usht* __restrict__ hist, float* __restrict__ fs) {
  __shared__ unsigned char hbuf[2 * 8 * 272];    // fp8 h, 8 rows, row stride 272, 2 parity
  int bid = blockIdx.x;
  int dir = bid & 1, rg = bid >> 1;              // rg in [0,16)
  int rowbase = rg * 8;
  int tid = threadIdx.x;
  int w = tid >> 6, l = tid & 63, lc = l & 15, q = l >> 4;
  int rh = q & 1;                                // row half: rows rh*4 .. rh*4+3
  int cc = q >> 1;                               // unit sub-column
  int ub = w * 32;                               // wave owns units ub..ub+31
  const unsigned char* Wb = WhhL + (size_t)dir * 196608u;
  long bfrag[3][2][8];                           // fp8 B-frags: 96 VGPRs, resident
#pragma unroll
  for (int g = 0; g < 3; ++g)
#pragma unroll
    for (int c2 = 0; c2 < 2; ++c2)
#pragma unroll
      for (int kt = 0; kt < 8; ++kt)
        bfrag[g][c2][kt] =
            *(const long*)(Wb + (size_t)(g * 256 + ub + c2 * 16 + lc) * 256 + kt * 32 + q * 8);
  const float* bhh = dir ? bhhb : bhhf;
  int jj = ub + cc * 16 + lc;                    // owned unit column
  float bhn = bhh[512 + jj];
  float hprev[4] = {0.f, 0.f, 0.f, 0.f};
  const usht* xp = xgp + (size_t)dir * 8388608u;
  int xoffb = (rowbase + rh * 4) * 1024 + jj * 4;        // shorts; + i*1024 per cell
  int hoffv = (rowbase + rh * 4) * 512 + dir * 256 + jj; // hist shorts; + i*512
  int hwa = (rh * 4) * 272 + jj;                 // hbuf write byte base; + i*272 + parity
  int hra = (lc & 7) * 272 + q * 8;              // hbuf A-read byte base; + kt*32 + parity

  ushort4 xs0[4], xs1[4], xs2[4], xs3[4];        // 4 static slots (rule #20)
  {                                              // prologue: prefetch steps 0,1,2
    int t0 = dir ? 63 : 0, t1 = dir ? 62 : 1, t2 = dir ? 61 : 2;
#pragma unroll
    for (int i = 0; i < 4; ++i) xs0[i] = *(const ushort4*)(xp + t0 * 131072 + xoffb + i * 1024);
#pragma unroll
    for (int i = 0; i < 4; ++i) xs1[i] = *(const ushort4*)(xp + t1 * 131072 + xoffb + i * 1024);
#pragma unroll
    for (int i = 0; i < 4; ++i) xs2[i] = *(const ushort4*)(xp + t2 * 131072 + xoffb + i * 1024);
  }
  const f32x4 zf4 = (f32x4){0.f, 0.f, 0.f, 0.f};

#define BODY(J, XC, XN)                                                              \
  {                                                                                  \
    const int s = it4 + (J);                                                         \
    const int tt = dir ? 63 - s : s;                                                 \
    {                                                                                \
      int sn = s + 3; if (sn > 63) sn = 63;                                          \
      int ttn = dir ? 63 - sn : sn;                                                  \
      const usht* pb = xp + ttn * 131072;                                            \
      _Pragma("unroll")                                                              \
      for (int i = 0; i < 4; ++i) XN[i] = *(const ushort4*)(pb + xoffb + i * 1024);  \
    }                                                                                \
    f32x4 acc[3][2];                                                                 \
    _Pragma("unroll")                                                                \
    for (int g = 0; g < 3; ++g) { acc[g][0] = zf4; acc[g][1] = zf4; }                \
    if ((J) != 0 || it4 != 0) {                                                      \
      const unsigned char* hb = hbuf + ((((J) & 1) ^ 1) * 2176);                     \
      _Pragma("unroll")                                                              \
      for (int kt = 0; kt < 8; ++kt) {                                               \
        long a = *(const long*)(hb + hra + kt * 32);                                 \
        _Pragma("unroll")                                                            \
        for (int g = 0; g < 3; ++g) {                                                \
          acc[g][0] = __builtin_amdgcn_mfma_f32_16x16x32_fp8_fp8(a, bfrag[g][0][kt], acc[g][0], 0, 0, 0); \
          acc[g][1] = __builtin_amdgcn_mfma_f32_16x16x32_fp8_fp8(a, bfrag[g][1][kt], acc[g][1], 0, 0, 0); \
        }                                                                            \
      }                                                                              \
    }                                                                                \
    f32x4 ar = cc ? acc[0][1] : acc[0][0];                                           \
    f32x4 az = cc ? acc[1][1] : acc[1][0];                                           \
    f32x4 an = cc ? acc[2][1] : acc[2][0];                                           \
    unsigned char* hw = hbuf + (((J) & 1) * 2176);                                   \
    float hv4[4];                                                                    \
    _Pragma("unroll")                                                                \
    for (int i = 0; i < 4; ++i) {                                                    \
      ushort4 xv = XC[i];                                                            \
      float rg_ = fsig(bf2f(xv.x) + ar[i]);                                          \
      float zg_ = fsig(bf2f(xv.y) + az[i]);                                          \
      float nn = ftanh(fmaf(rg_, an[i] + bhn, bf2f(xv.z)));                          \
      float hv = fmaf(zg_, hprev[i] - nn, nn);                                       \
      hprev[i] = hv;                                                                 \
      hv4[i] = hv;                                                                   \
      hw[hwa + i * 272] = f2fp8(hv);                                                 \
    }                                                                                \
    if (LAYER == 0) {                                                                \
      usht* hrow = hist + (size_t)tt * 65536 + hoffv;                                \
      _Pragma("unroll")                                                              \
      for (int i = 0; i < 4; ++i) hrow[i * 512] = f2bf(hv4[i]);                      \
    }                                                                                \
    if (LAYER == 1 && (J) == 3 && it4 == 60) {                                       \
      _Pragma("unroll")                                                              \
      for (int i = 0; i < 4; ++i) fs[hoffv - dir * 256 - jj + dir * 256 + jj + i * 512] = hv4[i]; \
    }                                                                                \
    asm volatile("s_waitcnt lgkmcnt(0)\ns_barrier" ::: "memory");                    \
  }

#pragma unroll 1
  for (int it = 0; it < 16; ++it) {
    int it4 = it * 4;
    BODY(0, xs0, xs3)
    BODY(1, xs1, xs0)
    BODY(2, xs2, xs1)
    BODY(3, xs3, xs2)
  }
#undef BODY
}

// ---------------- final projection: out[b][o] = fs[b][:] . proj_W[o][:] + pb[o] ----------------
__global__ __launch_bounds__(256) void proj_kernel(const float* fs, const float* pW,
                                                   const float* pb, float* out) {
  __shared__ float sf[512];
  int b = blockIdx.x, o = threadIdx.x;
  for (int k = o; k < 512; k += 256) sf[k] = fs[b * 512 + k];
  __syncthreads();
  const float* wr_ = pW + (size_t)o * 512;
  float s = 0.f;
#pragma unroll 4
  for (int k = 0; k < 512; k += 4) {
    float4 wv = *(const float4*)(wr_ + k);
    s += wv.x * sf[k] + wv.y * sf[k + 1] + wv.z * sf[k + 2] + wv.w * sf[k + 3];
  }
  out[(size_t)b * 256 + o] = s + pb[o];
}

extern "C" void kernel_launch(void* const* d_in, const int* in_sizes, int n_in,
                              void* d_out, int out_size, void* d_ws, size_t ws_size,
                              hipStream_t stream) {
  const int*   wi    = (const int*)d_in[0];
  const float* emb   = (const float*)d_in[1];
  const float* oove  = (const float*)d_in[2];
  const float* Wih0f = (const float*)d_in[3];
  const float* Whh0f = (const float*)d_in[4];
  const float* bih0f = (const float*)d_in[5];
  const float* bhh0f = (const float*)d_in[6];
  const float* Wih0b = (const float*)d_in[7];
  const float* Whh0b = (const float*)d_in[8];
  const float* bih0b = (const float*)d_in[9];
  const float* bhh0b = (const float*)d_in[10];
  const float* Wih1f = (const float*)d_in[11];
  const float* Whh1f = (const float*)d_in[12];
  const float* bih1f = (const float*)d_in[13];
  const float* bhh1f = (const float*)d_in[14];
  const float* Wih1b = (const float*)d_in[15];
  const float* Whh1b = (const float*)d_in[16];
  const float* bih1b = (const float*)d_in[17];
  const float* bhh1b = (const float*)d_in[18];
  const float* projW = (const float*)d_in[19];
  const float* projb = (const float*)d_in[20];

  char* ws = (char*)d_ws;
  usht*  w0   = (usht*)(ws + OFF_W0);
  usht*  w1   = (usht*)(ws + OFF_W1);
  unsigned char* whh = (unsigned char*)(ws + OFF_WHH);
  usht*  xb   = (usht*)(ws + OFF_X);
  usht*  xgp  = (usht*)(ws + OFF_XGP);
  usht*  hist = (usht*)(ws + OFF_HIST);
  float* fs   = (float*)(ws + OFF_FS);
  float* bias = (float*)(ws + OFF_BIAS);

  prep_kernel<<<dim3(1536, 9), 256, 0, stream>>>(
      Wih0f, Wih0b, Wih1f, Wih1b, Whh0f, Whh0b, Whh1f, Whh1b,
      bih0f, bhh0f, bih0b, bhh0b, bih1f, bhh1f, bih1b, bhh1b, ws);
  embed_kernel<<<1024, 256, 0, stream>>>(wi, emb, oove, xb);
  gemm_bt<256><<<dim3(64, 12), 256, 0, stream>>>(xb, w0, xgp, bias);
  recur_kernel<0><<<32, 512, 0, stream>>>(xgp, whh, bhh0f, bhh0b, hist, fs);
  gemm_bt<512><<<dim3(64, 12), 256, 0, stream>>>(hist, w1, xgp, bias + 1536);
  recur_kernel<1><<<32, 512, 0, stream>>>(xgp, whh + 2 * 196608, bhh1f, bhh1b, hist, fs);
  proj_kernel<<<128, 256, 0, stream>>>(fs, projW, projb, (float*)d_out);
}